// Round 1
// baseline (168.176 us; speedup 1.0000x reference)
//
#include <hip/hip_runtime.h>

// Problem constants (from reference): B=16, K=64, H=160, W=160
#define KK 64
#define HH 160
#define WW 160
#define HWPIX (HH * WW)   // 25600
#define EPSF 1e-5f

// One thread per output pixel (b, i, j). Each thread:
//  - reads 64 keypoints (staged in LDS, shared across the block's pixels)
//  - computes 64 gaussians via exp2 with log2(e) folded into coefficients
//  - keeps them in a 64-entry register array (fully unrolled)
//  - normalizes by (sum + EPS/den)  [den cancels algebraically]
//  - writes 64 coalesced dwords (stride H*W across k, contiguous across lanes)
__global__ __launch_bounds__(256) void recon_confmap_kernel(
    const float* __restrict__ kp,     // [B, K, 2]  (x, y)
    const float* __restrict__ sx_p,   // scalar
    const float* __restrict__ sy_p,   // scalar
    const float* __restrict__ rho_p,  // scalar
    float* __restrict__ out)          // [B, K, H, W]
{
    __shared__ float2 skp[KK];

    const int b   = blockIdx.y;
    const int tid = threadIdx.x;

    if (tid < KK) {
        // keypoints[b, k, :] as float2 (x, y)
        skp[tid] = ((const float2*)(kp + (size_t)b * KK * 2))[tid];
    }

    const float sx  = sx_p[0];
    const float sy  = sy_p[0];
    const float rho = rho_p[0];
    __syncthreads();

    // Fold num1 = -1/(2(1-rho^2)) and log2(e) into the quadratic coefficients:
    // scoreMap = den * exp(num1 * (dy^2/sy^2 + dx^2/sx^2 - 2rho/(sx sy) dy dx))
    // out      = e / (sum_k e + EPS/den)   -- den cancels against the sum
    const float L2E   = 1.44269504088896340736f;
    const float omr2  = 1.0f - rho * rho;
    const float num1  = -0.5f / omr2;
    const float ca    = num1 / (sy * sy) * L2E;            // * dy^2
    const float cb    = num1 / (sx * sx) * L2E;            // * dx^2
    const float cc    = num1 * (-2.0f * rho / (sx * sy)) * L2E; // * dy*dx
    const float epsod = EPSF * (2.0f * 3.14159265358979323846f * sx * sy * sqrtf(omr2));

    const int p  = blockIdx.x * 256 + tid;   // 0 .. H*W-1 (grid.x * 256 == H*W)
    const int i  = p / WW;
    const int j  = p - i * WW;
    const float fi = (float)i;
    const float fj = (float)j;

    float s[KK];
    float sum = 0.0f;
#pragma unroll
    for (int k = 0; k < KK; ++k) {
        const float dy  = fi - skp[k].y;
        const float dx  = fj - skp[k].x;
        const float arg = fmaf(ca * dy, dy, fmaf(cb * dx, dx, cc * dy * dx));
        const float e   = __builtin_amdgcn_exp2f(arg);
        s[k] = e;
        sum += e;
    }

    const float inv = 1.0f / (sum + epsod);

    float* op = out + (size_t)b * KK * HWPIX + p;
#pragma unroll
    for (int k = 0; k < KK; ++k) {
        op[(size_t)k * HWPIX] = s[k] * inv;
    }
}

extern "C" void kernel_launch(void* const* d_in, const int* in_sizes, int n_in,
                              void* d_out, int out_size, void* d_ws, size_t ws_size,
                              hipStream_t stream) {
    const float* kp    = (const float*)d_in[0];  // keypoints [B,K,2]
    const float* sx_p  = (const float*)d_in[1];
    const float* sy_p  = (const float*)d_in[2];
    const float* rho_p = (const float*)d_in[3];
    // d_in[4] = DetectionMap: values unused by the reference (shape only)
    float* out = (float*)d_out;

    const int B = in_sizes[0] / (KK * 2);   // 16
    dim3 grid(HWPIX / 256, B);              // (100, 16)
    recon_confmap_kernel<<<grid, 256, 0, stream>>>(kp, sx_p, sy_p, rho_p, out);
}